// Round 5
// baseline (450.707 us; speedup 1.0000x reference)
//
#include <hip/hip_runtime.h>

typedef __bf16 bf16;
typedef __bf16 bf16x8 __attribute__((ext_vector_type(8)));
typedef float f32x4 __attribute__((ext_vector_type(4)));

#define B_SZ   8
#define L_SEQ  1024
#define NH     16

// async global->LDS, 16B per lane; lds base wave-uniform, data lands at base+lane*16
__device__ __forceinline__ void lds_load16(bf16* lds, const bf16* g) {
  __builtin_amdgcn_global_load_lds(
      (const __attribute__((address_space(1))) void*)g,
      (__attribute__((address_space(3))) void*)lds, 16, 0, 0);
}

// load 8 contiguous f32 -> bf16x8
__device__ __forceinline__ bf16x8 cvt8(const float* __restrict__ p) {
  f32x4 a = *(const f32x4*)p;
  f32x4 b = *(const f32x4*)(p + 4);
  bf16x8 r;
  r[0] = (bf16)a[0]; r[1] = (bf16)a[1]; r[2] = (bf16)a[2]; r[3] = (bf16)a[3];
  r[4] = (bf16)b[0]; r[5] = (bf16)b[1]; r[6] = (bf16)b[2]; r[7] = (bf16)b[3];
  return r;
}

// ---------------------------------------------------------------------------
// Fused prep: one launch for all preprocessing.
// grid (4096, 4), 256 threads:
//  y=0/1/2            : convert Q/K/V f32->bf16 (4096*256*8 = 8388608 elems exact)
//  y=3, bx<512        : pack mask -> u64 bitmask (512*256 = 131072 words exact)
//  y=3, 512<=bx<2560  : convert WQ/WK/WV/WM (512 blocks each, 131072 x8 exact)
//  y=3, 2560<=bx<2688 : t_proj = T @ WT^T + bT (128 blocks x 64 rows)
// ---------------------------------------------------------------------------
__global__ __launch_bounds__(256) void prep_k(
    const float* __restrict__ Q, const float* __restrict__ K, const float* __restrict__ V,
    bf16* __restrict__ aq, bf16* __restrict__ ak, bf16* __restrict__ av,
    const int* __restrict__ mask, unsigned long long* __restrict__ mb64,
    const float* __restrict__ WQ, const float* __restrict__ WK,
    const float* __restrict__ WV, const float* __restrict__ WM,
    bf16* __restrict__ wq, bf16* __restrict__ wk, bf16* __restrict__ wv, bf16* __restrict__ wm,
    const float* __restrict__ T, const float* __restrict__ WT,
    const float* __restrict__ bT, bf16* __restrict__ tbuf) {
  const int bx = blockIdx.x;
  const int y  = blockIdx.y;
  const int tid = threadIdx.x;

  __shared__ __align__(16) bf16 t_s[64][72];
  __shared__ __align__(16) bf16 w_s[64][72];

  if (y < 3) {
    const float* in = (y == 0) ? Q : (y == 1) ? K : V;
    bf16* out       = (y == 0) ? aq : (y == 1) ? ak : av;
    size_t i = (size_t)bx * 256 + tid;
    *(bf16x8*)&out[i * 8] = cvt8(in + i * 8);
    return;
  }

  if (bx < 512) {
    // mask bit-pack: word[(b*L+row)*16 + kt], bit j = mask[..][kt*64+j] != 0
    int w = bx * 256 + tid;
    const int* base = mask + (size_t)w * 64;
    unsigned long long bits = 0;
    for (int j = 0; j < 64; j += 4) {
      int4 m4 = *(const int4*)(base + j);
      if (m4.x) bits |= 1ull << j;
      if (m4.y) bits |= 1ull << (j + 1);
      if (m4.z) bits |= 1ull << (j + 2);
      if (m4.w) bits |= 1ull << (j + 3);
    }
    mb64[w] = bits;
  } else if (bx < 2560) {
    int wsel = (bx - 512) >> 9;
    const float* in = (wsel == 0) ? WQ : (wsel == 1) ? WK : (wsel == 2) ? WV : WM;
    bf16* out       = (wsel == 0) ? wq : (wsel == 1) ? wk : (wsel == 2) ? wv : wm;
    size_t i = (size_t)((bx - 512) & 511) * 256 + tid;
    *(bf16x8*)&out[i * 8] = cvt8(in + i * 8);
  } else if (bx < 2688) {
    // t = T @ WT^T + bT   (64 rows per block)
    const int wave = tid >> 6;
    const int lane = tid & 63;
    const int quad = lane >> 4;
    const int l16  = lane & 15;
    const int row0 = (bx - 2560) * 64;

    for (int i = 0; i < 2; i++) {
      int c = tid + i * 256;
      int r = c >> 3;
      int cg = (c & 7) * 8;
      *(bf16x8*)&t_s[r][cg] = cvt8(T + (size_t)(row0 + r) * 64 + cg);
      *(bf16x8*)&w_s[r][cg] = cvt8(WT + (size_t)r * 64 + cg);
    }
    __syncthreads();

    f32x4 acc[4] = {};
    for (int ks = 0; ks < 2; ks++) {
      bf16x8 a = *(const bf16x8*)&t_s[wave * 16 + l16][ks * 32 + quad * 8];
      for (int nt = 0; nt < 4; nt++) {
        bf16x8 b = *(const bf16x8*)&w_s[nt * 16 + l16][ks * 32 + quad * 8];
        acc[nt] = __builtin_amdgcn_mfma_f32_16x16x32_bf16(a, b, acc[nt], 0, 0, 0);
      }
    }
    for (int nt = 0; nt < 4; nt++) {
      int col = nt * 16 + l16;
      float bv = bT[col];
      for (int r = 0; r < 4; r++) {
        int row = row0 + wave * 16 + quad * 4 + r;
        tbuf[(size_t)row * 64 + col] = (bf16)(acc[nt][r] + bv);
      }
    }
  }
}

// ---------------------------------------------------------------------------
// Fused Q/K/V projection GEMMs (proven): blockIdx.z selects.
// ---------------------------------------------------------------------------
__global__ __launch_bounds__(256) void gemm3(const bf16* __restrict__ aq,
                                             const bf16* __restrict__ ak,
                                             const bf16* __restrict__ av,
                                             const bf16* __restrict__ wq,
                                             const bf16* __restrict__ wk,
                                             const bf16* __restrict__ wv,
                                             const float* __restrict__ bq,
                                             const float* __restrict__ bk,
                                             const float* __restrict__ bv,
                                             bf16* __restrict__ oq,
                                             bf16* __restrict__ ok,
                                             bf16* __restrict__ ov) {
  const bf16* A; const bf16* W; const float* bias; bf16* out;
  switch (blockIdx.z) {
    case 0: A = aq; W = wq; bias = bq; out = oq; break;
    case 1: A = ak; W = wk; bias = bk; out = ok; break;
    default: A = av; W = wv; bias = bv; out = ov; break;
  }
  const int K = 1024, N = 1024;
  const int tid  = threadIdx.x;
  const int wave = tid >> 6;
  const int lane = tid & 63;
  const int quad = lane >> 4;
  const int l16  = lane & 15;
  const int wr   = wave >> 1;
  const int wc   = wave & 1;
  const int bm   = blockIdx.y * 128;
  const int bn   = blockIdx.x * 128;

  __shared__ __align__(16) bf16 a_s[128 * 64];
  __shared__ __align__(16) bf16 b_s[128 * 64];

  const int lrow = lane >> 3;
  const int lcol = (lane & 7) * 8;

  f32x4 acc[4][4] = {};

  for (int kt = 0; kt < K; kt += 64) {
    __syncthreads();
    for (int i = 0; i < 4; i++) {
      int c = wave * 4 + i;
      int row = c * 8 + lrow;
      lds_load16(&a_s[c * 512], &A[(size_t)(bm + row) * K + kt + lcol]);
      lds_load16(&b_s[c * 512], &W[(size_t)(bn + row) * K + kt + lcol]);
    }
    __syncthreads();

    for (int ks = 0; ks < 2; ks++) {
      bf16x8 af[4], bfr[4];
      for (int mt = 0; mt < 4; mt++)
        af[mt] = *(const bf16x8*)&a_s[(wr * 64 + mt * 16 + l16) * 64 + ks * 32 + quad * 8];
      for (int nt = 0; nt < 4; nt++)
        bfr[nt] = *(const bf16x8*)&b_s[(wc * 64 + nt * 16 + l16) * 64 + ks * 32 + quad * 8];
      for (int mt = 0; mt < 4; mt++)
        for (int nt = 0; nt < 4; nt++)
          acc[mt][nt] = __builtin_amdgcn_mfma_f32_16x16x32_bf16(af[mt], bfr[nt], acc[mt][nt], 0, 0, 0);
    }
  }

  for (int mt = 0; mt < 4; mt++) {
    for (int nt = 0; nt < 4; nt++) {
      int col = bn + wc * 64 + nt * 16 + l16;
      float bv2 = bias[col];
      for (int r = 0; r < 4; r++) {
        int i = bm + wr * 64 + mt * 16 + quad * 4 + r;
        out[(size_t)i * N + col] = (bf16)(acc[mt][nt][r] + bv2);
      }
    }
  }
}

// ---------------------------------------------------------------------------
// Final projection GEMM: out = A @ W^T + bias, f32 row-major out (to d_out).
// ---------------------------------------------------------------------------
__global__ __launch_bounds__(256) void gemm16(const bf16* __restrict__ A,
                                              const bf16* __restrict__ W,
                                              const float* __restrict__ bias,
                                              float* __restrict__ out,
                                              int M, int N, int K) {
  const int tid  = threadIdx.x;
  const int wave = tid >> 6;
  const int lane = tid & 63;
  const int quad = lane >> 4;
  const int l16  = lane & 15;
  const int wr   = wave >> 1;
  const int wc   = wave & 1;
  const int bm   = blockIdx.y * 128;
  const int bn   = blockIdx.x * 128;

  __shared__ __align__(16) bf16 a_s[128 * 64];
  __shared__ __align__(16) bf16 b_s[128 * 64];

  const int lrow = lane >> 3;
  const int lcol = (lane & 7) * 8;

  f32x4 acc[4][4] = {};

  for (int kt = 0; kt < K; kt += 64) {
    __syncthreads();
    for (int i = 0; i < 4; i++) {
      int c = wave * 4 + i;
      int row = c * 8 + lrow;
      lds_load16(&a_s[c * 512], &A[(size_t)(bm + row) * K + kt + lcol]);
      lds_load16(&b_s[c * 512], &W[(size_t)(bn + row) * K + kt + lcol]);
    }
    __syncthreads();

    for (int ks = 0; ks < 2; ks++) {
      bf16x8 af[4], bfr[4];
      for (int mt = 0; mt < 4; mt++)
        af[mt] = *(const bf16x8*)&a_s[(wr * 64 + mt * 16 + l16) * 64 + ks * 32 + quad * 8];
      for (int nt = 0; nt < 4; nt++)
        bfr[nt] = *(const bf16x8*)&b_s[(wc * 64 + nt * 16 + l16) * 64 + ks * 32 + quad * 8];
      for (int mt = 0; mt < 4; mt++)
        for (int nt = 0; nt < 4; nt++)
          acc[mt][nt] = __builtin_amdgcn_mfma_f32_16x16x32_bf16(af[mt], bfr[nt], acc[mt][nt], 0, 0, 0);
    }
  }

  for (int mt = 0; mt < 4; mt++) {
    for (int nt = 0; nt < 4; nt++) {
      int col = bn + wc * 64 + nt * 16 + l16;
      float bv = bias[col];
      for (int r = 0; r < 4; r++) {
        int i = bm + wr * 64 + mt * 16 + quad * 4 + r;
        out[(size_t)i * N + col] = acc[mt][nt][r] + bv;
      }
    }
  }
}

// ---------------------------------------------------------------------------
// Flash attention v2: q-tile=64 rows, 256 thr (4 waves), KVBLK=32.
// Same proven round-0 structure per wave (q frags in regs, inline mask loads,
// k/v register prefetch, padded LDS rows — NO swizzle, NO new index arrays),
// but smaller tiles so BOTH limits improve:
//   LDS = k_s[32][136] + v_s[64][40] + p_s[64][40] = 18944 B  (8 blk/CU cap)
//   regs: s_acc 4->2 f32x4 (-8) vs round 0; everything else identical
// -> expected 7-8 blocks/CU * 4 waves = 28-32 waves/CU vs 24 today, and grid
// 2048 blocks ~= one scheduling pass.
// REGISTER-CLIFF WARNING (measured r1-r3): cap is 512/6=85 combined
// VGPR+AGPR; adding index arrays / swizzle temps / hoisted masks spills qf
// to scratch (FETCH 80MB -> 0.5-1.1GB). Keep edits register-negative.
// ---------------------------------------------------------------------------
__global__ __launch_bounds__(256, 6) void attn(const bf16* __restrict__ qp,
                                               const bf16* __restrict__ kp,
                                               const bf16* __restrict__ vp,
                                               const bf16* __restrict__ tb,
                                               const unsigned long long* __restrict__ mb64,
                                               bf16* __restrict__ xout) {
  const int bh   = blockIdx.x;        // 0..127
  const int qt   = blockIdx.y;        // 0..15
  const int b    = bh >> 4;
  const int h    = bh & 15;
  const int tid  = threadIdx.x;
  const int wave = tid >> 6;          // 0..3
  const int lane = tid & 63;
  const int quad = lane >> 4;
  const int l16  = lane & 15;

  __shared__ __align__(16) bf16 k_s[32][136];   //  8704 B
  __shared__ __align__(16) bf16 v_s[64][40];    //  5120 B  [dv][l]
  __shared__ __align__(16) bf16 p_s[64][40];    //  5120 B  => 18944 total

  const bf16* qpb = qp + (size_t)(b * L_SEQ) * 1024 + h * 64;
  const bf16* kpb = kp + (size_t)(b * L_SEQ) * 1024 + h * 64;
  const bf16* vpb = vp + (size_t)(b * L_SEQ) * 1024 + h * 64;
  const bf16* tb0 = tb + (size_t)b * L_SEQ * 64;
  const unsigned long long* mrow = mb64 + (size_t)b * L_SEQ * 16;

  // q fragments in registers: A[m=l16][k=ks*32+quad*8 .. +7], m row = wave*16+l16
  bf16x8 qf[4];
  {
    int grow = qt * 64 + wave * 16 + l16;
    qf[0] = *(const bf16x8*)(qpb + (size_t)grow * 1024 + quad * 8);
    qf[1] = *(const bf16x8*)(qpb + (size_t)grow * 1024 + 32 + quad * 8);
    qf[2] = *(const bf16x8*)(tb0 + (size_t)grow * 64 + quad * 8);
    qf[3] = *(const bf16x8*)(tb0 + (size_t)grow * 64 + 32 + quad * 8);
  }

  // staging index maps: K tile 32x128 bf16 = 512 chunks -> 2/thread
  //                     V tile 32l x 64dv  = 2048 elems -> 8/thread
  const int k_row = tid >> 4, k_cg = tid & 15;   // rows 0..15 and 16..31
  const int v_l = tid & 31, v_dvb = (tid >> 5) * 8;

  bf16x8 kr0, kr1, vr;
  {
    const bf16* s0 = (k_cg < 8) ? (kpb + (size_t)k_row * 1024 + k_cg * 8)
                                : (tb0 + (size_t)k_row * 64 + (k_cg - 8) * 8);
    const bf16* s1 = (k_cg < 8) ? (kpb + (size_t)(k_row + 16) * 1024 + k_cg * 8)
                                : (tb0 + (size_t)(k_row + 16) * 64 + (k_cg - 8) * 8);
    kr0 = *(const bf16x8*)s0;
    kr1 = *(const bf16x8*)s1;
    vr  = *(const bf16x8*)&vpb[(size_t)v_l * 1024 + v_dvb];
  }

  f32x4 o[4] = {};
  float l_part[4] = {0.f, 0.f, 0.f, 0.f};

  const float C = 0.12751781f;   // 1/sqrt(128) * log2(e)
  const int qrow_base = qt * 64 + wave * 16 + quad * 4;

  for (int kt = 0; kt < 32; kt++) {
    __syncthreads();   // prior-iter reads of k_s/v_s done
    *(bf16x8*)&k_s[k_row][k_cg * 8] = kr0;
    *(bf16x8*)&k_s[k_row + 16][k_cg * 8] = kr1;
    for (int j = 0; j < 8; j++) v_s[v_dvb + j][v_l] = vr[j];
    __syncthreads();

    // S = q_cat @ k_cat^T (K=128, 32 k-cols); q from registers
    f32x4 s_acc[2] = {};
    for (int ks = 0; ks < 4; ks++) {
      for (int nt = 0; nt < 2; nt++) {
        bf16x8 bfr = *(const bf16x8*)&k_s[nt * 16 + l16][ks * 32 + quad * 8];
        s_acc[nt] = __builtin_amdgcn_mfma_f32_16x16x32_bf16(qf[ks], bfr, s_acc[nt], 0, 0, 0);
      }
    }

    // p = exp2(s*C) (masked -> 0); accumulate l partials; P -> LDS (own rows)
    // mask word covers 64 k-cols: word kt>>1, bit (kt&1)*32 + nt*16 + l16
    for (int r = 0; r < 4; r++) {
      unsigned long long wsh =
          mrow[(size_t)(qrow_base + r) * 16 + (kt >> 1)] >> (((kt & 1) << 5) + l16);
      for (int nt = 0; nt < 2; nt++) {
        float arg = s_acc[nt][r] * C;
        if ((wsh >> (nt * 16)) & 1ull) arg = -1e9f;
        float p = __builtin_amdgcn_exp2f(arg);
        l_part[r] += p;
        p_s[wave * 16 + quad * 4 + r][nt * 16 + l16] = (bf16)p;
      }
    }

    // prefetch kt+1 while PV runs
    if (kt < 31) {
      int gl0 = (kt + 1) * 32;
      const bf16* s0 = (k_cg < 8) ? (kpb + (size_t)(gl0 + k_row) * 1024 + k_cg * 8)
                                  : (tb0 + (size_t)(gl0 + k_row) * 64 + (k_cg - 8) * 8);
      const bf16* s1 = (k_cg < 8) ? (kpb + (size_t)(gl0 + k_row + 16) * 1024 + k_cg * 8)
                                  : (tb0 + (size_t)(gl0 + k_row + 16) * 64 + (k_cg - 8) * 8);
      kr0 = *(const bf16x8*)s0;
      kr1 = *(const bf16x8*)s1;
      vr  = *(const bf16x8*)&vpb[(size_t)(gl0 + v_l) * 1024 + v_dvb];
    }

    // O += P @ V (K=32)
    {
      bf16x8 a = *(const bf16x8*)&p_s[wave * 16 + l16][quad * 8];
      for (int nt = 0; nt < 4; nt++) {
        bf16x8 bfr = *(const bf16x8*)&v_s[nt * 16 + l16][quad * 8];
        o[nt] = __builtin_amdgcn_mfma_f32_16x16x32_bf16(a, bfr, o[nt], 0, 0, 0);
      }
    }
  }

  float inv_l[4];
  for (int r = 0; r < 4; r++) {
    float s = l_part[r];
    for (int off = 8; off >= 1; off >>= 1) s += __shfl_xor(s, off);
    inv_l[r] = 1.f / fmaxf(s, 1e-30f);
  }
  for (int nt = 0; nt < 4; nt++) {
    int col = h * 64 + nt * 16 + l16;
    for (int r = 0; r < 4; r++) {
      int row = qt * 64 + wave * 16 + quad * 4 + r;
      xout[((size_t)(b * L_SEQ + row)) * 1024 + col] = (bf16)(o[nt][r] * inv_l[r]);
    }
  }
}

// ---------------------------------------------------------------------------
extern "C" void kernel_launch(void* const* d_in, const int* in_sizes, int n_in,
                              void* d_out, int out_size, void* d_ws, size_t ws_size,
                              hipStream_t stream) {
  const float* Q    = (const float*)d_in[0];
  const float* K    = (const float*)d_in[1];
  const float* V    = (const float*)d_in[2];
  const float* T    = (const float*)d_in[3];
  const int*   mask = (const int*)d_in[4];
  const float* WQ = (const float*)d_in[5];
  const float* bQ = (const float*)d_in[6];
  const float* WK = (const float*)d_in[7];
  const float* bK = (const float*)d_in[8];
  const float* WV = (const float*)d_in[9];
  const float* bV = (const float*)d_in[10];
  const float* WM = (const float*)d_in[11];
  const float* bM = (const float*)d_in[12];
  const float* WT = (const float*)d_in[13];
  const float* bT = (const float*)d_in[14];

  const size_t NE = (size_t)B_SZ * NH * L_SEQ * 64;  // 8388608
  bf16* ws16 = (bf16*)d_ws;
  bf16* qp = ws16;                    // bf16 8192x1024
  bf16* kp = ws16 + NE;
  bf16* vp = ws16 + 2 * NE;
  bf16* tb = ws16 + 3 * NE;           // 524288
  unsigned long long* mb64 = (unsigned long long*)(ws16 + 3 * NE + 524288);
  bf16* wq = ws16 + 3 * NE + 1048576;
  bf16* wk = wq + 1048576;
  bf16* wv = wk + 1048576;
  bf16* wm = wv + 1048576;
  bf16* av = wm + 1048576;            // gemm3 V-input scratch, then attn output
  bf16* aq = (bf16*)d_out;            // d_out as A-conversion scratch (dead after gemm3)
  bf16* ak = (bf16*)d_out + NE;
  bf16* xa = av;                      // attn bf16 output reuses av slot
  float* fout = (float*)d_out;        // final GEMM writes d_out directly

  dim3 blk(256);

  prep_k<<<dim3(4096, 4), blk, 0, stream>>>(Q, K, V, aq, ak, av, mask, mb64,
                                            WQ, WK, WV, WM, wq, wk, wv, wm,
                                            T, WT, bT, tb);
  gemm3<<<dim3(8, 64, 3), blk, 0, stream>>>(aq, ak, av, wq, wk, wv, bQ, bK, bV, qp, kp, vp);
  attn<<<dim3(128, 16), dim3(256), 0, stream>>>(qp, kp, vp, tb, mb64, xa);
  gemm16<<<dim3(8, 64), blk, 0, stream>>>(xa, wm, bM, fout, 8192, 1024, 1024);
}

// Round 6
// 411.415 us; speedup vs baseline: 1.0955x; 1.0955x over previous
//
#include <hip/hip_runtime.h>

typedef __bf16 bf16;
typedef __bf16 bf16x8 __attribute__((ext_vector_type(8)));
typedef float f32x4 __attribute__((ext_vector_type(4)));

#define B_SZ   8
#define L_SEQ  1024
#define NH     16

// async global->LDS, 16B per lane; lds base wave-uniform, data lands at base+lane*16
__device__ __forceinline__ void lds_load16(bf16* lds, const bf16* g) {
  __builtin_amdgcn_global_load_lds(
      (const __attribute__((address_space(1))) void*)g,
      (__attribute__((address_space(3))) void*)lds, 16, 0, 0);
}

// load 8 contiguous f32 -> bf16x8
__device__ __forceinline__ bf16x8 cvt8(const float* __restrict__ p) {
  f32x4 a = *(const f32x4*)p;
  f32x4 b = *(const f32x4*)(p + 4);
  bf16x8 r;
  r[0] = (bf16)a[0]; r[1] = (bf16)a[1]; r[2] = (bf16)a[2]; r[3] = (bf16)a[3];
  r[4] = (bf16)b[0]; r[5] = (bf16)b[1]; r[6] = (bf16)b[2]; r[7] = (bf16)b[3];
  return r;
}

// ---------------------------------------------------------------------------
// Fused prep: one launch for all preprocessing.
// grid (4096, 4), 256 threads:
//  y=0/1/2            : convert Q/K/V f32->bf16 (4096*256*8 = 8388608 elems exact)
//  y=3, bx<512        : pack mask -> u64 bitmask (512*256 = 131072 words exact)
//  y=3, 512<=bx<2560  : convert WQ/WK/WV/WM (512 blocks each, 131072 x8 exact)
//  y=3, 2560<=bx<2688 : t_proj = T @ WT^T + bT (128 blocks x 64 rows)
// ---------------------------------------------------------------------------
__global__ __launch_bounds__(256) void prep_k(
    const float* __restrict__ Q, const float* __restrict__ K, const float* __restrict__ V,
    bf16* __restrict__ aq, bf16* __restrict__ ak, bf16* __restrict__ av,
    const int* __restrict__ mask, unsigned long long* __restrict__ mb64,
    const float* __restrict__ WQ, const float* __restrict__ WK,
    const float* __restrict__ WV, const float* __restrict__ WM,
    bf16* __restrict__ wq, bf16* __restrict__ wk, bf16* __restrict__ wv, bf16* __restrict__ wm,
    const float* __restrict__ T, const float* __restrict__ WT,
    const float* __restrict__ bT, bf16* __restrict__ tbuf) {
  const int bx = blockIdx.x;
  const int y  = blockIdx.y;
  const int tid = threadIdx.x;

  __shared__ __align__(16) bf16 t_s[64][72];
  __shared__ __align__(16) bf16 w_s[64][72];

  if (y < 3) {
    const float* in = (y == 0) ? Q : (y == 1) ? K : V;
    bf16* out       = (y == 0) ? aq : (y == 1) ? ak : av;
    size_t i = (size_t)bx * 256 + tid;
    *(bf16x8*)&out[i * 8] = cvt8(in + i * 8);
    return;
  }

  if (bx < 512) {
    // mask bit-pack: word[(b*L+row)*16 + kt], bit j = mask[..][kt*64+j] != 0
    int w = bx * 256 + tid;
    const int* base = mask + (size_t)w * 64;
    unsigned long long bits = 0;
    for (int j = 0; j < 64; j += 4) {
      int4 m4 = *(const int4*)(base + j);
      if (m4.x) bits |= 1ull << j;
      if (m4.y) bits |= 1ull << (j + 1);
      if (m4.z) bits |= 1ull << (j + 2);
      if (m4.w) bits |= 1ull << (j + 3);
    }
    mb64[w] = bits;
  } else if (bx < 2560) {
    int wsel = (bx - 512) >> 9;
    const float* in = (wsel == 0) ? WQ : (wsel == 1) ? WK : (wsel == 2) ? WV : WM;
    bf16* out       = (wsel == 0) ? wq : (wsel == 1) ? wk : (wsel == 2) ? wv : wm;
    size_t i = (size_t)((bx - 512) & 511) * 256 + tid;
    *(bf16x8*)&out[i * 8] = cvt8(in + i * 8);
  } else if (bx < 2688) {
    // t = T @ WT^T + bT   (64 rows per block)
    const int wave = tid >> 6;
    const int lane = tid & 63;
    const int quad = lane >> 4;
    const int l16  = lane & 15;
    const int row0 = (bx - 2560) * 64;

    for (int i = 0; i < 2; i++) {
      int c = tid + i * 256;
      int r = c >> 3;
      int cg = (c & 7) * 8;
      *(bf16x8*)&t_s[r][cg] = cvt8(T + (size_t)(row0 + r) * 64 + cg);
      *(bf16x8*)&w_s[r][cg] = cvt8(WT + (size_t)r * 64 + cg);
    }
    __syncthreads();

    f32x4 acc[4] = {};
    for (int ks = 0; ks < 2; ks++) {
      bf16x8 a = *(const bf16x8*)&t_s[wave * 16 + l16][ks * 32 + quad * 8];
      for (int nt = 0; nt < 4; nt++) {
        bf16x8 b = *(const bf16x8*)&w_s[nt * 16 + l16][ks * 32 + quad * 8];
        acc[nt] = __builtin_amdgcn_mfma_f32_16x16x32_bf16(a, b, acc[nt], 0, 0, 0);
      }
    }
    for (int nt = 0; nt < 4; nt++) {
      int col = nt * 16 + l16;
      float bv = bT[col];
      for (int r = 0; r < 4; r++) {
        int row = row0 + wave * 16 + quad * 4 + r;
        tbuf[(size_t)row * 64 + col] = (bf16)(acc[nt][r] + bv);
      }
    }
  }
}

// ---------------------------------------------------------------------------
// Fused Q/K/V projection GEMMs (proven): blockIdx.z selects.
// XCD-aware block swizzle (T1): 512 wgs/slice, dispatch round-robins linear
// id across 8 XCDs; remap so XCD k gets a contiguous chunk (8 m-tiles x all
// n-tiles) -> each A-panel lives on ONE XCD L2, B panel L2-resident per XCD.
// ---------------------------------------------------------------------------
__global__ __launch_bounds__(256) void gemm3(const bf16* __restrict__ aq,
                                             const bf16* __restrict__ ak,
                                             const bf16* __restrict__ av,
                                             const bf16* __restrict__ wq,
                                             const bf16* __restrict__ wk,
                                             const bf16* __restrict__ wv,
                                             const float* __restrict__ bq,
                                             const float* __restrict__ bk,
                                             const float* __restrict__ bv,
                                             bf16* __restrict__ oq,
                                             bf16* __restrict__ ok,
                                             bf16* __restrict__ ov) {
  const bf16* A; const bf16* W; const float* bias; bf16* out;
  switch (blockIdx.z) {
    case 0: A = aq; W = wq; bias = bq; out = oq; break;
    case 1: A = ak; W = wk; bias = bk; out = ok; break;
    default: A = av; W = wv; bias = bv; out = ov; break;
  }
  const int K = 1024, N = 1024;
  const int tid  = threadIdx.x;
  const int wave = tid >> 6;
  const int lane = tid & 63;
  const int quad = lane >> 4;
  const int l16  = lane & 15;
  const int wr   = wave >> 1;
  const int wc   = wave & 1;

  // XCD swizzle: lin 0..511 bijective -> (bm,bn) chunked per XCD
  const int lin = blockIdx.y * 8 + blockIdx.x;
  const int swz = (lin & 7) * 64 + (lin >> 3);
  const int bm  = (swz >> 3) * 128;
  const int bn  = (swz & 7) * 128;

  __shared__ __align__(16) bf16 a_s[128 * 64];
  __shared__ __align__(16) bf16 b_s[128 * 64];

  const int lrow = lane >> 3;
  const int lcol = (lane & 7) * 8;

  f32x4 acc[4][4] = {};

  for (int kt = 0; kt < K; kt += 64) {
    __syncthreads();
    for (int i = 0; i < 4; i++) {
      int c = wave * 4 + i;
      int row = c * 8 + lrow;
      lds_load16(&a_s[c * 512], &A[(size_t)(bm + row) * K + kt + lcol]);
      lds_load16(&b_s[c * 512], &W[(size_t)(bn + row) * K + kt + lcol]);
    }
    __syncthreads();

    for (int ks = 0; ks < 2; ks++) {
      bf16x8 af[4], bfr[4];
      for (int mt = 0; mt < 4; mt++)
        af[mt] = *(const bf16x8*)&a_s[(wr * 64 + mt * 16 + l16) * 64 + ks * 32 + quad * 8];
      for (int nt = 0; nt < 4; nt++)
        bfr[nt] = *(const bf16x8*)&b_s[(wc * 64 + nt * 16 + l16) * 64 + ks * 32 + quad * 8];
      for (int mt = 0; mt < 4; mt++)
        for (int nt = 0; nt < 4; nt++)
          acc[mt][nt] = __builtin_amdgcn_mfma_f32_16x16x32_bf16(af[mt], bfr[nt], acc[mt][nt], 0, 0, 0);
    }
  }

  for (int mt = 0; mt < 4; mt++) {
    for (int nt = 0; nt < 4; nt++) {
      int col = bn + wc * 64 + nt * 16 + l16;
      float bv2 = bias[col];
      for (int r = 0; r < 4; r++) {
        int i = bm + wr * 64 + mt * 16 + quad * 4 + r;
        out[(size_t)i * N + col] = (bf16)(acc[mt][nt][r] + bv2);
      }
    }
  }
}

// ---------------------------------------------------------------------------
// Final projection GEMM: out = A @ W^T + bias, f32 row-major out (to d_out).
// Same XCD swizzle as gemm3 (grid is (8,64) fixed).
// ---------------------------------------------------------------------------
__global__ __launch_bounds__(256) void gemm16(const bf16* __restrict__ A,
                                              const bf16* __restrict__ W,
                                              const float* __restrict__ bias,
                                              float* __restrict__ out,
                                              int M, int N, int K) {
  const int tid  = threadIdx.x;
  const int wave = tid >> 6;
  const int lane = tid & 63;
  const int quad = lane >> 4;
  const int l16  = lane & 15;
  const int wr   = wave >> 1;
  const int wc   = wave & 1;

  const int lin = blockIdx.y * 8 + blockIdx.x;
  const int swz = (lin & 7) * 64 + (lin >> 3);
  const int bm  = (swz >> 3) * 128;
  const int bn  = (swz & 7) * 128;

  __shared__ __align__(16) bf16 a_s[128 * 64];
  __shared__ __align__(16) bf16 b_s[128 * 64];

  const int lrow = lane >> 3;
  const int lcol = (lane & 7) * 8;

  f32x4 acc[4][4] = {};

  for (int kt = 0; kt < K; kt += 64) {
    __syncthreads();
    for (int i = 0; i < 4; i++) {
      int c = wave * 4 + i;
      int row = c * 8 + lrow;
      lds_load16(&a_s[c * 512], &A[(size_t)(bm + row) * K + kt + lcol]);
      lds_load16(&b_s[c * 512], &W[(size_t)(bn + row) * K + kt + lcol]);
    }
    __syncthreads();

    for (int ks = 0; ks < 2; ks++) {
      bf16x8 af[4], bfr[4];
      for (int mt = 0; mt < 4; mt++)
        af[mt] = *(const bf16x8*)&a_s[(wr * 64 + mt * 16 + l16) * 64 + ks * 32 + quad * 8];
      for (int nt = 0; nt < 4; nt++)
        bfr[nt] = *(const bf16x8*)&b_s[(wc * 64 + nt * 16 + l16) * 64 + ks * 32 + quad * 8];
      for (int mt = 0; mt < 4; mt++)
        for (int nt = 0; nt < 4; nt++)
          acc[mt][nt] = __builtin_amdgcn_mfma_f32_16x16x32_bf16(af[mt], bfr[nt], acc[mt][nt], 0, 0, 0);
    }
  }

  for (int mt = 0; mt < 4; mt++) {
    for (int nt = 0; nt < 4; nt++) {
      int col = bn + wc * 64 + nt * 16 + l16;
      float bv = bias[col];
      for (int r = 0; r < 4; r++) {
        int i = bm + wr * 64 + mt * 16 + quad * 4 + r;
        out[(size_t)i * N + col] = acc[mt][nt][r] + bv;
      }
    }
  }
}

// ---------------------------------------------------------------------------
// Flash attention (round-0 proven version, EXACT): q-tile=128 rows, 512 thr,
// q fragments in registers, no online max, deferred l-reduction, k/v register
// prefetch. LDS 45 KB (padded rows) -> 3 blocks/CU.
// MEASURED FACTS (r1-r5):
//  - Register cliff: cap = 512/6 = 85 combined VGPR+AGPR; reported VGPR 40 +
//    ~40 AGPR acc sits AT the cliff. Any added live state (index arrays,
//    swizzle temps, hoisted masks) spills qf: FETCH 80MB -> 0.5-1.1GB.
//  - NOT occupancy-bound: r5's small-tile variant (8 blk/CU LDS cap, one
//    exact pass, no spill) was SLOWER (159us) at the same ~50% measured
//    occupancy. The limiter is the barrier-to-barrier critical path per KV
//    iteration (softmax VALU ~2.5x MFMA issue time). Do not re-tile.
// ---------------------------------------------------------------------------
__global__ __launch_bounds__(512, 6) void attn(const bf16* __restrict__ qp,
                                               const bf16* __restrict__ kp,
                                               const bf16* __restrict__ vp,
                                               const bf16* __restrict__ tb,
                                               const unsigned long long* __restrict__ mb64,
                                               bf16* __restrict__ xout) {
  const int bh   = blockIdx.x;        // 0..127
  const int qt   = blockIdx.y;        // 0..7
  const int b    = bh >> 4;
  const int h    = bh & 15;
  const int tid  = threadIdx.x;
  const int wave = tid >> 6;          // 0..7
  const int lane = tid & 63;
  const int quad = lane >> 4;
  const int l16  = lane & 15;

  __shared__ __align__(16) bf16 k_s[64][136];   // 17408 B
  __shared__ __align__(16) bf16 v_s[64][72];    //  9216 B  [dv][l]
  __shared__ __align__(16) bf16 p_s[128][72];   // 18432 B  => 45056 total, 3 blk/CU

  const bf16* qpb = qp + (size_t)(b * L_SEQ) * 1024 + h * 64;
  const bf16* kpb = kp + (size_t)(b * L_SEQ) * 1024 + h * 64;
  const bf16* vpb = vp + (size_t)(b * L_SEQ) * 1024 + h * 64;
  const bf16* tb0 = tb + (size_t)b * L_SEQ * 64;
  const unsigned long long* mrow = mb64 + (size_t)b * L_SEQ * 16;

  // q fragments in registers: A[m=l16][k=ks*32+quad*8 .. +7], m row = wave*16+l16
  bf16x8 qf[4];
  {
    int grow = qt * 128 + wave * 16 + l16;
    qf[0] = *(const bf16x8*)(qpb + (size_t)grow * 1024 + quad * 8);
    qf[1] = *(const bf16x8*)(qpb + (size_t)grow * 1024 + 32 + quad * 8);
    qf[2] = *(const bf16x8*)(tb0 + (size_t)grow * 64 + quad * 8);
    qf[3] = *(const bf16x8*)(tb0 + (size_t)grow * 64 + 32 + quad * 8);
  }

  // staging index maps (k tile: 2 chunks/thread; v tile: 1 chunk/thread)
  const int kc0_row = tid >> 4,         kc0_cg = tid & 15;
  const int kc1_row = (tid + 512) >> 4, kc1_cg = (tid + 512) & 15;
  const int v_l = tid & 63, v_dvb = (tid >> 6) * 8;

  bf16x8 kr0, kr1, vr;
  {
    const bf16* s0 = (kc0_cg < 8) ? (kpb + (size_t)kc0_row * 1024 + kc0_cg * 8)
                                  : (tb0 + (size_t)kc0_row * 64 + (kc0_cg - 8) * 8);
    const bf16* s1 = (kc1_cg < 8) ? (kpb + (size_t)kc1_row * 1024 + kc1_cg * 8)
                                  : (tb0 + (size_t)kc1_row * 64 + (kc1_cg - 8) * 8);
    kr0 = *(const bf16x8*)s0;
    kr1 = *(const bf16x8*)s1;
    vr  = *(const bf16x8*)&vpb[(size_t)v_l * 1024 + v_dvb];
  }

  f32x4 o[4] = {};
  float l_part[4] = {0.f, 0.f, 0.f, 0.f};

  const float C = 0.12751781f;   // 1/sqrt(128) * log2(e)
  const int qrow_base = qt * 128 + wave * 16 + quad * 4;

  for (int kt = 0; kt < 16; kt++) {
    __syncthreads();   // prior-iter reads of k_s/v_s done
    *(bf16x8*)&k_s[kc0_row][kc0_cg * 8] = kr0;
    *(bf16x8*)&k_s[kc1_row][kc1_cg * 8] = kr1;
    for (int j = 0; j < 8; j++) v_s[v_dvb + j][v_l] = vr[j];
    __syncthreads();

    // S = q_cat @ k_cat^T (K=128); q from registers
    f32x4 s_acc[4] = {};
    for (int ks = 0; ks < 4; ks++) {
      for (int nt = 0; nt < 4; nt++) {
        bf16x8 bfr = *(const bf16x8*)&k_s[nt * 16 + l16][ks * 32 + quad * 8];
        s_acc[nt] = __builtin_amdgcn_mfma_f32_16x16x32_bf16(qf[ks], bfr, s_acc[nt], 0, 0, 0);
      }
    }

    // p = exp2(s*C) (masked -> 0); accumulate l partials; P -> LDS (own rows)
    for (int r = 0; r < 4; r++) {
      unsigned long long wsh = mrow[(size_t)(qrow_base + r) * 16 + kt] >> l16;
      for (int nt = 0; nt < 4; nt++) {
        float arg = s_acc[nt][r] * C;
        if ((wsh >> (nt * 16)) & 1ull) arg = -1e9f;
        float p = __builtin_amdgcn_exp2f(arg);
        l_part[r] += p;
        p_s[wave * 16 + quad * 4 + r][nt * 16 + l16] = (bf16)p;
      }
    }

    // prefetch kt+1 while PV runs
    if (kt < 15) {
      int gl0 = (kt + 1) * 64;
      const bf16* s0 = (kc0_cg < 8) ? (kpb + (size_t)(gl0 + kc0_row) * 1024 + kc0_cg * 8)
                                    : (tb0 + (size_t)(gl0 + kc0_row) * 64 + (kc0_cg - 8) * 8);
      const bf16* s1 = (kc1_cg < 8) ? (kpb + (size_t)(gl0 + kc1_row) * 1024 + kc1_cg * 8)
                                    : (tb0 + (size_t)(gl0 + kc1_row) * 64 + (kc1_cg - 8) * 8);
      kr0 = *(const bf16x8*)s0;
      kr1 = *(const bf16x8*)s1;
      vr  = *(const bf16x8*)&vpb[(size_t)(gl0 + v_l) * 1024 + v_dvb];
    }

    // O += P @ V (K=64)
    for (int ks = 0; ks < 2; ks++) {
      bf16x8 a = *(const bf16x8*)&p_s[wave * 16 + l16][ks * 32 + quad * 8];
      for (int nt = 0; nt < 4; nt++) {
        bf16x8 bfr = *(const bf16x8*)&v_s[nt * 16 + l16][ks * 32 + quad * 8];
        o[nt] = __builtin_amdgcn_mfma_f32_16x16x32_bf16(a, bfr, o[nt], 0, 0, 0);
      }
    }
  }

  float inv_l[4];
  for (int r = 0; r < 4; r++) {
    float s = l_part[r];
    for (int off = 8; off >= 1; off >>= 1) s += __shfl_xor(s, off);
    inv_l[r] = 1.f / fmaxf(s, 1e-30f);
  }
  for (int nt = 0; nt < 4; nt++) {
    int col = h * 64 + nt * 16 + l16;
    for (int r = 0; r < 4; r++) {
      int row = qt * 128 + wave * 16 + quad * 4 + r;
      xout[((size_t)(b * L_SEQ + row)) * 1024 + col] = (bf16)(o[nt][r] * inv_l[r]);
    }
  }
}

// ---------------------------------------------------------------------------
extern "C" void kernel_launch(void* const* d_in, const int* in_sizes, int n_in,
                              void* d_out, int out_size, void* d_ws, size_t ws_size,
                              hipStream_t stream) {
  const float* Q    = (const float*)d_in[0];
  const float* K    = (const float*)d_in[1];
  const float* V    = (const float*)d_in[2];
  const float* T    = (const float*)d_in[3];
  const int*   mask = (const int*)d_in[4];
  const float* WQ = (const float*)d_in[5];
  const float* bQ = (const float*)d_in[6];
  const float* WK = (const float*)d_in[7];
  const float* bK = (const float*)d_in[8];
  const float* WV = (const float*)d_in[9];
  const float* bV = (const float*)d_in[10];
  const float* WM = (const float*)d_in[11];
  const float* bM = (const float*)d_in[12];
  const float* WT = (const float*)d_in[13];
  const float* bT = (const float*)d_in[14];

  const size_t NE = (size_t)B_SZ * NH * L_SEQ * 64;  // 8388608
  bf16* ws16 = (bf16*)d_ws;
  bf16* qp = ws16;                    // bf16 8192x1024
  bf16* kp = ws16 + NE;
  bf16* vp = ws16 + 2 * NE;
  bf16* tb = ws16 + 3 * NE;           // 524288
  unsigned long long* mb64 = (unsigned long long*)(ws16 + 3 * NE + 524288);
  bf16* wq = ws16 + 3 * NE + 1048576;
  bf16* wk = wq + 1048576;
  bf16* wv = wk + 1048576;
  bf16* wm = wv + 1048576;
  bf16* av = wm + 1048576;            // gemm3 V-input scratch, then attn output
  bf16* aq = (bf16*)d_out;            // d_out as A-conversion scratch (dead after gemm3)
  bf16* ak = (bf16*)d_out + NE;
  bf16* xa = av;                      // attn bf16 output reuses av slot
  float* fout = (float*)d_out;        // final GEMM writes d_out directly

  dim3 blk(256);

  prep_k<<<dim3(4096, 4), blk, 0, stream>>>(Q, K, V, aq, ak, av, mask, mb64,
                                            WQ, WK, WV, WM, wq, wk, wv, wm,
                                            T, WT, bT, tb);
  gemm3<<<dim3(8, 64, 3), blk, 0, stream>>>(aq, ak, av, wq, wk, wv, bQ, bK, bV, qp, kp, vp);
  attn<<<dim3(128, 8), dim3(512), 0, stream>>>(qp, kp, vp, tb, mb64, xa);
  gemm16<<<dim3(8, 64), blk, 0, stream>>>(xa, wm, bM, fout, 8192, 1024, 1024);
}

// Round 7
// 392.174 us; speedup vs baseline: 1.1493x; 1.0491x over previous
//
#include <hip/hip_runtime.h>

typedef __bf16 bf16;
typedef __bf16 bf16x4 __attribute__((ext_vector_type(4)));
typedef __bf16 bf16x8 __attribute__((ext_vector_type(8)));
typedef float f32x4 __attribute__((ext_vector_type(4)));

#define B_SZ   8
#define L_SEQ  1024
#define NH     16

// async global->LDS, 16B per lane; lds base wave-uniform, data lands at base+lane*16
__device__ __forceinline__ void lds_load16(bf16* lds, const bf16* g) {
  __builtin_amdgcn_global_load_lds(
      (const __attribute__((address_space(1))) void*)g,
      (__attribute__((address_space(3))) void*)lds, 16, 0, 0);
}

// load 8 contiguous f32 -> bf16x8
__device__ __forceinline__ bf16x8 cvt8(const float* __restrict__ p) {
  f32x4 a = *(const f32x4*)p;
  f32x4 b = *(const f32x4*)(p + 4);
  bf16x8 r;
  r[0] = (bf16)a[0]; r[1] = (bf16)a[1]; r[2] = (bf16)a[2]; r[3] = (bf16)a[3];
  r[4] = (bf16)b[0]; r[5] = (bf16)b[1]; r[6] = (bf16)b[2]; r[7] = (bf16)b[3];
  return r;
}

// ---------------------------------------------------------------------------
// Fused prep: one launch for all preprocessing.
// grid (4096, 4), 256 threads:
//  y=0/1/2            : convert Q/K/V f32->bf16 (4096*256*8 = 8388608 elems exact)
//  y=3, bx<512        : pack mask -> u64 bitmask (512*256 = 131072 words exact)
//  y=3, 512<=bx<2560  : convert WQ/WK/WV/WM (512 blocks each, 131072 x8 exact)
//  y=3, 2560<=bx<2688 : t_proj = T @ WT^T + bT (128 blocks x 64 rows)
// ---------------------------------------------------------------------------
__global__ __launch_bounds__(256) void prep_k(
    const float* __restrict__ Q, const float* __restrict__ K, const float* __restrict__ V,
    bf16* __restrict__ aq, bf16* __restrict__ ak, bf16* __restrict__ av,
    const int* __restrict__ mask, unsigned long long* __restrict__ mb64,
    const float* __restrict__ WQ, const float* __restrict__ WK,
    const float* __restrict__ WV, const float* __restrict__ WM,
    bf16* __restrict__ wq, bf16* __restrict__ wk, bf16* __restrict__ wv, bf16* __restrict__ wm,
    const float* __restrict__ T, const float* __restrict__ WT,
    const float* __restrict__ bT, bf16* __restrict__ tbuf) {
  const int bx = blockIdx.x;
  const int y  = blockIdx.y;
  const int tid = threadIdx.x;

  __shared__ __align__(16) bf16 t_s[64][72];
  __shared__ __align__(16) bf16 w_s[64][72];

  if (y < 3) {
    const float* in = (y == 0) ? Q : (y == 1) ? K : V;
    bf16* out       = (y == 0) ? aq : (y == 1) ? ak : av;
    size_t i = (size_t)bx * 256 + tid;
    *(bf16x8*)&out[i * 8] = cvt8(in + i * 8);
    return;
  }

  if (bx < 512) {
    // mask bit-pack: word[(b*L+row)*16 + kt], bit j = mask[..][kt*64+j] != 0
    int w = bx * 256 + tid;
    const int* base = mask + (size_t)w * 64;
    unsigned long long bits = 0;
    for (int j = 0; j < 64; j += 4) {
      int4 m4 = *(const int4*)(base + j);
      if (m4.x) bits |= 1ull << j;
      if (m4.y) bits |= 1ull << (j + 1);
      if (m4.z) bits |= 1ull << (j + 2);
      if (m4.w) bits |= 1ull << (j + 3);
    }
    mb64[w] = bits;
  } else if (bx < 2560) {
    int wsel = (bx - 512) >> 9;
    const float* in = (wsel == 0) ? WQ : (wsel == 1) ? WK : (wsel == 2) ? WV : WM;
    bf16* out       = (wsel == 0) ? wq : (wsel == 1) ? wk : (wsel == 2) ? wv : wm;
    size_t i = (size_t)((bx - 512) & 511) * 256 + tid;
    *(bf16x8*)&out[i * 8] = cvt8(in + i * 8);
  } else if (bx < 2688) {
    // t = T @ WT^T + bT   (64 rows per block)
    const int wave = tid >> 6;
    const int lane = tid & 63;
    const int quad = lane >> 4;
    const int l16  = lane & 15;
    const int row0 = (bx - 2560) * 64;

    for (int i = 0; i < 2; i++) {
      int c = tid + i * 256;
      int r = c >> 3;
      int cg = (c & 7) * 8;
      *(bf16x8*)&t_s[r][cg] = cvt8(T + (size_t)(row0 + r) * 64 + cg);
      *(bf16x8*)&w_s[r][cg] = cvt8(WT + (size_t)r * 64 + cg);
    }
    __syncthreads();

    f32x4 acc[4] = {};
    for (int ks = 0; ks < 2; ks++) {
      bf16x8 a = *(const bf16x8*)&t_s[wave * 16 + l16][ks * 32 + quad * 8];
      for (int nt = 0; nt < 4; nt++) {
        bf16x8 b = *(const bf16x8*)&w_s[nt * 16 + l16][ks * 32 + quad * 8];
        acc[nt] = __builtin_amdgcn_mfma_f32_16x16x32_bf16(a, b, acc[nt], 0, 0, 0);
      }
    }
    for (int nt = 0; nt < 4; nt++) {
      int col = nt * 16 + l16;
      float bv = bT[col];
      for (int r = 0; r < 4; r++) {
        int row = row0 + wave * 16 + quad * 4 + r;
        tbuf[(size_t)row * 64 + col] = (bf16)(acc[nt][r] + bv);
      }
    }
  }
}

// ---------------------------------------------------------------------------
// Fused Q/K/V projection GEMMs (proven): blockIdx.z selects.
// XCD-aware block swizzle (T1): measured NEUTRAL (r6) but harmless; kept.
// ---------------------------------------------------------------------------
__global__ __launch_bounds__(256) void gemm3(const bf16* __restrict__ aq,
                                             const bf16* __restrict__ ak,
                                             const bf16* __restrict__ av,
                                             const bf16* __restrict__ wq,
                                             const bf16* __restrict__ wk,
                                             const bf16* __restrict__ wv,
                                             const float* __restrict__ bq,
                                             const float* __restrict__ bk,
                                             const float* __restrict__ bv,
                                             bf16* __restrict__ oq,
                                             bf16* __restrict__ ok,
                                             bf16* __restrict__ ov) {
  const bf16* A; const bf16* W; const float* bias; bf16* out;
  switch (blockIdx.z) {
    case 0: A = aq; W = wq; bias = bq; out = oq; break;
    case 1: A = ak; W = wk; bias = bk; out = ok; break;
    default: A = av; W = wv; bias = bv; out = ov; break;
  }
  const int K = 1024, N = 1024;
  const int tid  = threadIdx.x;
  const int wave = tid >> 6;
  const int lane = tid & 63;
  const int quad = lane >> 4;
  const int l16  = lane & 15;
  const int wr   = wave >> 1;
  const int wc   = wave & 1;

  // XCD swizzle: lin 0..511 bijective -> (bm,bn) chunked per XCD
  const int lin = blockIdx.y * 8 + blockIdx.x;
  const int swz = (lin & 7) * 64 + (lin >> 3);
  const int bm  = (swz >> 3) * 128;
  const int bn  = (swz & 7) * 128;

  __shared__ __align__(16) bf16 a_s[128 * 64];
  __shared__ __align__(16) bf16 b_s[128 * 64];

  const int lrow = lane >> 3;
  const int lcol = (lane & 7) * 8;

  f32x4 acc[4][4] = {};

  for (int kt = 0; kt < K; kt += 64) {
    __syncthreads();
    for (int i = 0; i < 4; i++) {
      int c = wave * 4 + i;
      int row = c * 8 + lrow;
      lds_load16(&a_s[c * 512], &A[(size_t)(bm + row) * K + kt + lcol]);
      lds_load16(&b_s[c * 512], &W[(size_t)(bn + row) * K + kt + lcol]);
    }
    __syncthreads();

    for (int ks = 0; ks < 2; ks++) {
      bf16x8 af[4], bfr[4];
      for (int mt = 0; mt < 4; mt++)
        af[mt] = *(const bf16x8*)&a_s[(wr * 64 + mt * 16 + l16) * 64 + ks * 32 + quad * 8];
      for (int nt = 0; nt < 4; nt++)
        bfr[nt] = *(const bf16x8*)&b_s[(wc * 64 + nt * 16 + l16) * 64 + ks * 32 + quad * 8];
      for (int mt = 0; mt < 4; mt++)
        for (int nt = 0; nt < 4; nt++)
          acc[mt][nt] = __builtin_amdgcn_mfma_f32_16x16x32_bf16(af[mt], bfr[nt], acc[mt][nt], 0, 0, 0);
    }
  }

  for (int mt = 0; mt < 4; mt++) {
    for (int nt = 0; nt < 4; nt++) {
      int col = bn + wc * 64 + nt * 16 + l16;
      float bv2 = bias[col];
      for (int r = 0; r < 4; r++) {
        int i = bm + wr * 64 + mt * 16 + quad * 4 + r;
        out[(size_t)i * N + col] = (bf16)(acc[mt][nt][r] + bv2);
      }
    }
  }
}

// ---------------------------------------------------------------------------
// Final projection GEMM: out = A @ W^T + bias, f32 row-major out (to d_out).
// Same XCD swizzle as gemm3 (grid is (8,64) fixed).
// ---------------------------------------------------------------------------
__global__ __launch_bounds__(256) void gemm16(const bf16* __restrict__ A,
                                              const bf16* __restrict__ W,
                                              const float* __restrict__ bias,
                                              float* __restrict__ out,
                                              int M, int N, int K) {
  const int tid  = threadIdx.x;
  const int wave = tid >> 6;
  const int lane = tid & 63;
  const int quad = lane >> 4;
  const int l16  = lane & 15;
  const int wr   = wave >> 1;
  const int wc   = wave & 1;

  const int lin = blockIdx.y * 8 + blockIdx.x;
  const int swz = (lin & 7) * 64 + (lin >> 3);
  const int bm  = (swz >> 3) * 128;
  const int bn  = (swz & 7) * 128;

  __shared__ __align__(16) bf16 a_s[128 * 64];
  __shared__ __align__(16) bf16 b_s[128 * 64];

  const int lrow = lane >> 3;
  const int lcol = (lane & 7) * 8;

  f32x4 acc[4][4] = {};

  for (int kt = 0; kt < K; kt += 64) {
    __syncthreads();
    for (int i = 0; i < 4; i++) {
      int c = wave * 4 + i;
      int row = c * 8 + lrow;
      lds_load16(&a_s[c * 512], &A[(size_t)(bm + row) * K + kt + lcol]);
      lds_load16(&b_s[c * 512], &W[(size_t)(bn + row) * K + kt + lcol]);
    }
    __syncthreads();

    for (int ks = 0; ks < 2; ks++) {
      bf16x8 af[4], bfr[4];
      for (int mt = 0; mt < 4; mt++)
        af[mt] = *(const bf16x8*)&a_s[(wr * 64 + mt * 16 + l16) * 64 + ks * 32 + quad * 8];
      for (int nt = 0; nt < 4; nt++)
        bfr[nt] = *(const bf16x8*)&b_s[(wc * 64 + nt * 16 + l16) * 64 + ks * 32 + quad * 8];
      for (int mt = 0; mt < 4; mt++)
        for (int nt = 0; nt < 4; nt++)
          acc[mt][nt] = __builtin_amdgcn_mfma_f32_16x16x32_bf16(af[mt], bfr[nt], acc[mt][nt], 0, 0, 0);
    }
  }

  for (int mt = 0; mt < 4; mt++) {
    for (int nt = 0; nt < 4; nt++) {
      int col = bn + wc * 64 + nt * 16 + l16;
      float bv = bias[col];
      for (int r = 0; r < 4; r++) {
        int i = bm + wr * 64 + mt * 16 + quad * 4 + r;
        out[(size_t)i * N + col] = acc[mt][nt][r] + bv;
      }
    }
  }
}

// ---------------------------------------------------------------------------
// Flash attention v3: q-tile=256 rows, 1024 thr (16 waves), KVBLK=64.
// Per-wave inner loop is byte-identical to the proven round-0 structure
// (16 q-rows/wave, qf[4] in regs, inline mask loads, k/v register prefetch,
// padded LDS rows). The ONLY change is amortization: 2x q-rows per block
// halves barrier-iterations (16384 -> 8192 total) and halves K/V staging
// per output row. r5 measured the inverse (half tile -> 1.37x slower), so
// the barrier/staging fixed cost is the limiter, not occupancy/pipes/banks.
// Staging state SHRINKS per thread (1 K-chunk not 2, bf16x4 V not x8):
// register-negative, and __launch_bounds__(1024,1) caps at 256 regs -> no
// spill possible (r1-r3 cliff does not apply).
// LDS = k_s[64][136] + v_s[64][72] + p_s[256][72] = 63488 B (<64KB static),
// 1 block/CU, grid 512 = 2 exact passes.
// MEASURED FACTS: r5 small-tile = slower (159us); r6 bank conflicts 0.02%
// of cycles (non-issue); XCD swizzle on GEMMs neutral.
// ---------------------------------------------------------------------------
__global__ __launch_bounds__(1024, 1) void attn(const bf16* __restrict__ qp,
                                                const bf16* __restrict__ kp,
                                                const bf16* __restrict__ vp,
                                                const bf16* __restrict__ tb,
                                                const unsigned long long* __restrict__ mb64,
                                                bf16* __restrict__ xout) {
  const int bh   = blockIdx.x;        // 0..127
  const int qt   = blockIdx.y;        // 0..3
  const int b    = bh >> 4;
  const int h    = bh & 15;
  const int tid  = threadIdx.x;
  const int wave = tid >> 6;          // 0..15
  const int lane = tid & 63;
  const int quad = lane >> 4;
  const int l16  = lane & 15;

  __shared__ __align__(16) bf16 k_s[64][136];   // 17408 B
  __shared__ __align__(16) bf16 v_s[64][72];    //  9216 B  [dv][l]
  __shared__ __align__(16) bf16 p_s[256][72];   // 36864 B  => 63488 total

  const bf16* qpb = qp + (size_t)(b * L_SEQ) * 1024 + h * 64;
  const bf16* kpb = kp + (size_t)(b * L_SEQ) * 1024 + h * 64;
  const bf16* vpb = vp + (size_t)(b * L_SEQ) * 1024 + h * 64;
  const bf16* tb0 = tb + (size_t)b * L_SEQ * 64;
  const unsigned long long* mrow = mb64 + (size_t)b * L_SEQ * 16;

  // q fragments in registers: A[m=l16][k=ks*32+quad*8 .. +7], m row = wave*16+l16
  bf16x8 qf[4];
  {
    int grow = qt * 256 + wave * 16 + l16;
    qf[0] = *(const bf16x8*)(qpb + (size_t)grow * 1024 + quad * 8);
    qf[1] = *(const bf16x8*)(qpb + (size_t)grow * 1024 + 32 + quad * 8);
    qf[2] = *(const bf16x8*)(tb0 + (size_t)grow * 64 + quad * 8);
    qf[3] = *(const bf16x8*)(tb0 + (size_t)grow * 64 + 32 + quad * 8);
  }

  // staging index maps (1024 threads):
  //  K tile 64x128 bf16 = 1024 16B-chunks -> exactly 1 chunk/thread
  //  V tile 64l x 64dv  = 4096 bf16       -> 4/thread (bf16x4, 8B load)
  const int k_row = tid >> 4, k_cg = tid & 15;
  const int v_l = tid & 63, v_dvb = (tid >> 6) * 4;

  bf16x8 kr;
  bf16x4 vr;
  {
    const bf16* s0 = (k_cg < 8) ? (kpb + (size_t)k_row * 1024 + k_cg * 8)
                                : (tb0 + (size_t)k_row * 64 + (k_cg - 8) * 8);
    kr = *(const bf16x8*)s0;
    vr = *(const bf16x4*)&vpb[(size_t)v_l * 1024 + v_dvb];
  }

  f32x4 o[4] = {};
  float l_part[4] = {0.f, 0.f, 0.f, 0.f};

  const float C = 0.12751781f;   // 1/sqrt(128) * log2(e)
  const int qrow_base = qt * 256 + wave * 16 + quad * 4;

  for (int kt = 0; kt < 16; kt++) {
    __syncthreads();   // prior-iter reads of k_s/v_s done
    *(bf16x8*)&k_s[k_row][k_cg * 8] = kr;
    for (int j = 0; j < 4; j++) v_s[v_dvb + j][v_l] = vr[j];
    __syncthreads();

    // S = q_cat @ k_cat^T (K=128); q from registers
    f32x4 s_acc[4] = {};
    for (int ks = 0; ks < 4; ks++) {
      for (int nt = 0; nt < 4; nt++) {
        bf16x8 bfr = *(const bf16x8*)&k_s[nt * 16 + l16][ks * 32 + quad * 8];
        s_acc[nt] = __builtin_amdgcn_mfma_f32_16x16x32_bf16(qf[ks], bfr, s_acc[nt], 0, 0, 0);
      }
    }

    // p = exp2(s*C) (masked -> 0); accumulate l partials; P -> LDS (own rows)
    for (int r = 0; r < 4; r++) {
      unsigned long long wsh = mrow[(size_t)(qrow_base + r) * 16 + kt] >> l16;
      for (int nt = 0; nt < 4; nt++) {
        float arg = s_acc[nt][r] * C;
        if ((wsh >> (nt * 16)) & 1ull) arg = -1e9f;
        float p = __builtin_amdgcn_exp2f(arg);
        l_part[r] += p;
        p_s[wave * 16 + quad * 4 + r][nt * 16 + l16] = (bf16)p;
      }
    }

    // prefetch kt+1 while PV runs
    if (kt < 15) {
      int gl0 = (kt + 1) * 64;
      const bf16* s0 = (k_cg < 8) ? (kpb + (size_t)(gl0 + k_row) * 1024 + k_cg * 8)
                                  : (tb0 + (size_t)(gl0 + k_row) * 64 + (k_cg - 8) * 8);
      kr = *(const bf16x8*)s0;
      vr = *(const bf16x4*)&vpb[(size_t)(gl0 + v_l) * 1024 + v_dvb];
    }

    // O += P @ V (K=64)
    for (int ks = 0; ks < 2; ks++) {
      bf16x8 a = *(const bf16x8*)&p_s[wave * 16 + l16][ks * 32 + quad * 8];
      for (int nt = 0; nt < 4; nt++) {
        bf16x8 bfr = *(const bf16x8*)&v_s[nt * 16 + l16][ks * 32 + quad * 8];
        o[nt] = __builtin_amdgcn_mfma_f32_16x16x32_bf16(a, bfr, o[nt], 0, 0, 0);
      }
    }
  }

  float inv_l[4];
  for (int r = 0; r < 4; r++) {
    float s = l_part[r];
    for (int off = 8; off >= 1; off >>= 1) s += __shfl_xor(s, off);
    inv_l[r] = 1.f / fmaxf(s, 1e-30f);
  }
  for (int nt = 0; nt < 4; nt++) {
    int col = h * 64 + nt * 16 + l16;
    for (int r = 0; r < 4; r++) {
      int row = qt * 256 + wave * 16 + quad * 4 + r;
      xout[((size_t)(b * L_SEQ + row)) * 1024 + col] = (bf16)(o[nt][r] * inv_l[r]);
    }
  }
}

// ---------------------------------------------------------------------------
extern "C" void kernel_launch(void* const* d_in, const int* in_sizes, int n_in,
                              void* d_out, int out_size, void* d_ws, size_t ws_size,
                              hipStream_t stream) {
  const float* Q    = (const float*)d_in[0];
  const float* K    = (const float*)d_in[1];
  const float* V    = (const float*)d_in[2];
  const float* T    = (const float*)d_in[3];
  const int*   mask = (const int*)d_in[4];
  const float* WQ = (const float*)d_in[5];
  const float* bQ = (const float*)d_in[6];
  const float* WK = (const float*)d_in[7];
  const float* bK = (const float*)d_in[8];
  const float* WV = (const float*)d_in[9];
  const float* bV = (const float*)d_in[10];
  const float* WM = (const float*)d_in[11];
  const float* bM = (const float*)d_in[12];
  const float* WT = (const float*)d_in[13];
  const float* bT = (const float*)d_in[14];

  const size_t NE = (size_t)B_SZ * NH * L_SEQ * 64;  // 8388608
  bf16* ws16 = (bf16*)d_ws;
  bf16* qp = ws16;                    // bf16 8192x1024
  bf16* kp = ws16 + NE;
  bf16* vp = ws16 + 2 * NE;
  bf16* tb = ws16 + 3 * NE;           // 524288
  unsigned long long* mb64 = (unsigned long long*)(ws16 + 3 * NE + 524288);
  bf16* wq = ws16 + 3 * NE + 1048576;
  bf16* wk = wq + 1048576;
  bf16* wv = wk + 1048576;
  bf16* wm = wv + 1048576;
  bf16* av = wm + 1048576;            // gemm3 V-input scratch, then attn output
  bf16* aq = (bf16*)d_out;            // d_out as A-conversion scratch (dead after gemm3)
  bf16* ak = (bf16*)d_out + NE;
  bf16* xa = av;                      // attn bf16 output reuses av slot
  float* fout = (float*)d_out;        // final GEMM writes d_out directly

  dim3 blk(256);

  prep_k<<<dim3(4096, 4), blk, 0, stream>>>(Q, K, V, aq, ak, av, mask, mb64,
                                            WQ, WK, WV, WM, wq, wk, wv, wm,
                                            T, WT, bT, tb);
  gemm3<<<dim3(8, 64, 3), blk, 0, stream>>>(aq, ak, av, wq, wk, wv, bQ, bK, bV, qp, kp, vp);
  attn<<<dim3(128, 4), dim3(1024), 0, stream>>>(qp, kp, vp, tb, mb64, xa);
  gemm16<<<dim3(8, 64), blk, 0, stream>>>(xa, wm, bM, fout, 8192, 1024, 1024);
}